// Round 13
// baseline (6576.135 us; speedup 1.0000x reference)
//
#include <hip/hip_runtime.h>
#include <math.h>

#define TT 2048
#define HH 64
#define NE 4       // batch elems per block
#define NBLK 128   // 512 / NE
#define NTHR 512   // 8 waves: 0-3 = L0 (elem wv), 4-7 = L1 (unit group wv-4)

typedef _Float16 half2_t __attribute__((ext_vector_type(2)));
typedef _Float16 half4_t __attribute__((ext_vector_type(4)));
typedef _Float16 half8 __attribute__((ext_vector_type(8)));
typedef float f32x4 __attribute__((ext_vector_type(4)));

__device__ __forceinline__ float sigmoid_fast(float x) {
    float e = __expf(-x);
    return __builtin_amdgcn_rcpf(1.0f + e);
}
__device__ __forceinline__ float tanh_fast(float x) {
    float e = __expf(-2.0f * x);
    return fmaf(2.0f, __builtin_amdgcn_rcpf(1.0f + e), -1.0f);
}
__device__ __forceinline__ float fdot2u(unsigned int a, unsigned int b, float c) {
    return __builtin_amdgcn_fdot2(__builtin_bit_cast(half2_t, a),
                                  __builtin_bit_cast(half2_t, b), c, false);
}
__device__ __forceinline__ unsigned int pack2(float a, float b) {
    half2_t h; h[0] = (_Float16)a; h[1] = (_Float16)b;
    return __builtin_bit_cast(unsigned int, h);
}

// Round 13: hybrid wave specialization, ONE barrier/step, minimal LDS traffic.
// r12 lesson: every MFMA wave redundantly reads the same h frags (16 waves x
// 4KB = 512 cyc/step LDS BW) + 2 barriers -> doubling waves changed nothing.
// New split: waves 0-3 = layer-0 for elem e=wv, pure fdot2 in-wave: lane l
// owns unit l's 4 gate rows of Whh0 (128 packed-fp16 uints, pinned), gates =
// 128 v_dot2_f32_f16, activation lane-local (1 unit/lane, 10 trans), h0
// rebroadcast via wave-local LDS round-trip (lgkmcnt only — the critical
// recurrence never crosses a barrier). Waves 4-7 = layer-1 by MFMA (r9
// layout: wave owns units [16j,16j+16), 4 gate tiles x 4 chained MFMAs,
// C-frag lane-local update), skewed one step: at step t computes gates1(t-1)
// from h0(t-1) + h1(t-2) (ping-pong swizzled LDS). One __syncthreads/step.
__global__ __launch_bounds__(NTHR, 2) __attribute__((amdgpu_waves_per_eu(2, 2)))
void lstm_hybrid_kernel(const float* __restrict__ x,      // [B,T]
                        const float* __restrict__ w_ih0,  // [256,1]
                        const float* __restrict__ w_hh0,  // [256,64]
                        const float* __restrict__ b_ih0,  // [256]
                        const float* __restrict__ b_hh0,  // [256]
                        const float* __restrict__ w_ih1,  // [256,64]
                        const float* __restrict__ w_hh1,  // [256,64]
                        const float* __restrict__ b_ih1,  // [256]
                        const float* __restrict__ b_hh1,  // [256]
                        const float* __restrict__ w1, const float* __restrict__ b1,
                        const float* __restrict__ w2, const float* __restrict__ b2,
                        const float* __restrict__ w3, const float* __restrict__ b3,
                        float* __restrict__ out)          // [B,10]
{
    const int tid = threadIdx.x;
    const int wv  = tid >> 6;        // wave 0..7
    const int l   = tid & 63;
    const int bA  = blockIdx.x * NE;
    const bool isL0 = (wv < 4);
    const int e   = wv;              // L0: owned elem
    const int j1  = wv & 3;          // L1: owned unit group [16j1, 16j1+16)
    const int e16 = l & 15;          // L1: MFMA col (elem; valid < NE)
    const int kg  = l >> 4;          // L1: k-group / C row-quad

    __shared__ __align__(16) float xs[NE * TT];            // [e][t] 32 KB
    __shared__ __align__(16) _Float16 h0sw[2][16 * 64];    // swizzled, ping-pong
    __shared__ __align__(16) _Float16 h1sw[2][16 * 64];
    __shared__ __align__(16) _Float16 h0lin[NE][64];       // linear, L0 self-reread
    __shared__ float cls1[NE][HH];
    __shared__ float cls2[NE][32];

    // zero swizzled buffers (rows 4..15 stay zero forever -> benign B cols)
    for (int i = tid; i < 2 * 16 * 64; i += NTHR) {
        ((_Float16*)h0sw)[i] = (_Float16)0.0f;
        ((_Float16*)h1sw)[i] = (_Float16)0.0f;
    }
    // stage x as [e][t] (coalesced read, linear write)
    for (int i = tid; i < NE * TT; i += NTHR) {
        const int ee = i >> 11, t = i & (TT - 1);
        xs[i] = x[(size_t)(bA + ee) * TT + t];
    }

    // ---- L0 weights: lane l owns rows {g*64+l} of Whh0, packed fp16 ----
    unsigned int w0p[4][32];
    float bi0[4], wx0[4];
    // ---- L1 weights: A-frags for (g, j1): Wih1 2 + Whh1 2 per gate ----
    half8 wf[16];
    f32x4 bf[4];
    if (isL0) {
        #pragma unroll
        for (int g = 0; g < 4; ++g) {
            const int row = g * 64 + l;
            const float2* wr = (const float2*)(w_hh0 + row * HH);
            #pragma unroll
            for (int p = 0; p < 32; ++p) {
                float2 v = wr[p];
                w0p[g][p] = pack2(v.x, v.y);
            }
            bi0[g] = b_ih0[row] + b_hh0[row];
            wx0[g] = w_ih0[row];
        }
        #pragma unroll
        for (int g = 0; g < 4; ++g) {
            #pragma unroll
            for (int p = 0; p < 32; ++p) asm volatile("" : "+v"(w0p[g][p]));
            asm volatile("" : "+v"(bi0[g]));
            asm volatile("" : "+v"(wx0[g]));
        }
    } else {
        auto frag = [&](const float* M, int g, int kc) {
            const int row = g * 64 + 16 * j1 + e16;   // A-frag row = l&15
            half8 v;
            #pragma unroll
            for (int i = 0; i < 8; ++i) v[i] = (_Float16)M[row * HH + kc * 32 + kg * 8 + i];
            return v;
        };
        #pragma unroll
        for (int g = 0; g < 4; ++g) {
            wf[g * 4 + 0] = frag(w_ih1, g, 0);
            wf[g * 4 + 1] = frag(w_ih1, g, 1);
            wf[g * 4 + 2] = frag(w_hh1, g, 0);
            wf[g * 4 + 3] = frag(w_hh1, g, 1);
            #pragma unroll
            for (int r = 0; r < 4; ++r) {
                const int row = g * 64 + 16 * j1 + 4 * kg + r;
                bf[g][r] = b_ih1[row] + b_hh1[row];
            }
        }
        #pragma unroll
        for (int g = 0; g < 4; ++g) {
            asm volatile("" : "+v"(wf[g * 4 + 0]));
            asm volatile("" : "+v"(wf[g * 4 + 1]));
            asm volatile("" : "+v"(wf[g * 4 + 2]));
            asm volatile("" : "+v"(wf[g * 4 + 3]));
            asm volatile("" : "+v"(bf[g]));
        }
    }

    // L0 state: packed h0(t-1) broadcast (32 uints), cell c0 (unit l, elem e)
    unsigned int hp[32];
    #pragma unroll
    for (int p = 0; p < 32; ++p) hp[p] = 0u;
    float c0 = 0.0f;
    // L1 state: 4 cells (units 16j1+4kg+r, elem e16)
    float cst[4] = {0.0f, 0.0f, 0.0f, 0.0f};

    const int swz16 = (e16 & 7) << 4;
    const int hro0 = e16 * 128 + ((16 * kg) ^ swz16);
    const int hro1 = e16 * 128 + ((64 + 16 * kg) ^ swz16);
    const int swzE = (e & 7) << 4;

    __syncthreads();

    for (int t = 0; t <= TT; ++t) {
        if (isL0) {
            if (t < TT) {
                const float xt = xs[e * TT + t];
                float a0 = fmaf(wx0[0], xt, bi0[0]);
                float a1 = fmaf(wx0[1], xt, bi0[1]);
                float a2 = fmaf(wx0[2], xt, bi0[2]);
                float a3 = fmaf(wx0[3], xt, bi0[3]);
                #pragma unroll
                for (int p = 0; p < 32; ++p) {
                    const unsigned int hh = hp[p];
                    a0 = fdot2u(w0p[0][p], hh, a0);
                    a1 = fdot2u(w0p[1][p], hh, a1);
                    a2 = fdot2u(w0p[2][p], hh, a2);
                    a3 = fdot2u(w0p[3][p], hh, a3);
                }
                const float gi = sigmoid_fast(a0);
                const float gf = sigmoid_fast(a1);
                const float gg = tanh_fast(a2);
                const float go = sigmoid_fast(a3);
                c0 = fmaf(gf, c0, gi * gg);
                const _Float16 h16 = (_Float16)(go * tanh_fast(c0));
                // publish: linear (self re-read) + swizzled (L1 frags, buf t&1)
                h0lin[e][l] = h16;
                *(_Float16*)((char*)&h0sw[t & 1][0] + e * 128 + ((2 * l) ^ swzE)) = h16;
                // reload broadcast h0(t) for next step (same wave, lgkmcnt only)
                #pragma unroll
                for (int q = 0; q < 8; ++q) {
                    uint4 v = ((const uint4*)&h0lin[e][0])[q];
                    hp[4 * q + 0] = v.x; hp[4 * q + 1] = v.y;
                    hp[4 * q + 2] = v.z; hp[4 * q + 3] = v.w;
                }
            }
        } else {
            if (t >= 1) {
                const int rb = (t - 1) & 1;
                const char* h0r = (const char*)&h0sw[rb][0];
                const char* h1r = (const char*)&h1sw[rb][0];
                half8 f0 = *(const half8*)(h0r + hro0);
                half8 f1 = *(const half8*)(h0r + hro1);
                half8 f2 = *(const half8*)(h1r + hro0);
                half8 f3 = *(const half8*)(h1r + hro1);
                f32x4 acc[4];
                #pragma unroll
                for (int g = 0; g < 4; ++g) {
                    acc[g] = __builtin_amdgcn_mfma_f32_16x16x32_f16(wf[g * 4 + 0], f0, bf[g], 0, 0, 0);
                    acc[g] = __builtin_amdgcn_mfma_f32_16x16x32_f16(wf[g * 4 + 1], f1, acc[g], 0, 0, 0);
                    acc[g] = __builtin_amdgcn_mfma_f32_16x16x32_f16(wf[g * 4 + 2], f2, acc[g], 0, 0, 0);
                    acc[g] = __builtin_amdgcn_mfma_f32_16x16x32_f16(wf[g * 4 + 3], f3, acc[g], 0, 0, 0);
                }
                half4_t hv;
                #pragma unroll
                for (int r = 0; r < 4; ++r) {
                    const float gi = sigmoid_fast(acc[0][r]);
                    const float gf = sigmoid_fast(acc[1][r]);
                    const float gg = tanh_fast(acc[2][r]);
                    const float go = sigmoid_fast(acc[3][r]);
                    const float c  = fmaf(gf, cst[r], gi * gg);
                    cst[r] = c;
                    hv[r] = (_Float16)(go * tanh_fast(c));
                }
                if (e16 < NE) {
                    char* hw = (char*)&h1sw[t & 1][0];
                    const int u0 = 16 * j1 + 4 * kg;
                    *(half4_t*)(hw + e16 * 128 + ((2 * u0) ^ swz16)) = hv;
                }
            }
        }
        __syncthreads();
    }
    // h_last = h1(TT-1), written at t=TT into buf 0 (TT even)

    // ---- classifier head: wave wv<4 handles elem wv ----
    if (wv < 4) {
        float a = b1[l];
        #pragma unroll 8
        for (int k = 0; k < HH; ++k) {
            const float hk = (float)*(const _Float16*)((const char*)&h1sw[0][0]
                                + wv * 128 + ((2 * k) ^ (wv << 4)));
            a = fmaf(w1[l * HH + k], hk, a);
        }
        cls1[wv][l] = fmaxf(a, 0.0f);
    }
    __syncthreads();
    if (wv < 4 && l < 32) {
        float a = b2[l];
        #pragma unroll 8
        for (int k = 0; k < HH; ++k) a = fmaf(w2[l * HH + k], cls1[wv][k], a);
        cls2[wv][l] = fmaxf(a, 0.0f);
    }
    __syncthreads();
    if (wv < 4 && l < 10) {
        float a = b3[l];
        #pragma unroll
        for (int k = 0; k < 32; ++k) a = fmaf(w3[l * 32 + k], cls2[wv][k], a);
        out[(size_t)(bA + wv) * 10 + l] = a;
    }
}

extern "C" void kernel_launch(void* const* d_in, const int* in_sizes, int n_in,
                              void* d_out, int out_size, void* d_ws, size_t ws_size,
                              hipStream_t stream) {
    const float* x     = (const float*)d_in[0];
    const float* w_ih0 = (const float*)d_in[1];
    const float* w_hh0 = (const float*)d_in[2];
    const float* b_ih0 = (const float*)d_in[3];
    const float* b_hh0 = (const float*)d_in[4];
    const float* w_ih1 = (const float*)d_in[5];
    const float* w_hh1 = (const float*)d_in[6];
    const float* b_ih1 = (const float*)d_in[7];
    const float* b_hh1 = (const float*)d_in[8];
    const float* w1    = (const float*)d_in[9];
    const float* b1    = (const float*)d_in[10];
    const float* w2    = (const float*)d_in[11];
    const float* b2    = (const float*)d_in[12];
    const float* w3    = (const float*)d_in[13];
    const float* b3    = (const float*)d_in[14];
    float* out = (float*)d_out;

    lstm_hybrid_kernel<<<NBLK, NTHR, 0, stream>>>(x, w_ih0, w_hh0, b_ih0, b_hh0,
                                                  w_ih1, w_hh1, b_ih1, b_hh1,
                                                  w1, b1, w2, b2, w3, b3, out);
}

// Round 14
// 2229.478 us; speedup vs baseline: 2.9496x; 2.9496x over previous
//
#include <hip/hip_runtime.h>
#include <math.h>

#define TT 2048
#define HH 64
#define NBLK 64    // 512 elems / 8 per block
#define NTHR 512   // 8 waves

typedef _Float16 half8 __attribute__((ext_vector_type(8)));
typedef float f32x4 __attribute__((ext_vector_type(4)));

__device__ __forceinline__ float sigmoid_fast(float x) {
    float e = __expf(-x);
    return __builtin_amdgcn_rcpf(1.0f + e);
}
__device__ __forceinline__ float tanh_fast(float x) {
    float e = __expf(-2.0f * x);
    return fmaf(2.0f, __builtin_amdgcn_rcpf(1.0f + e), -1.0f);
}

// Round 14: anti-phase quad pipelining. 64 blocks x 8 waves, 8 elems/block as
// two quads (P=elems 0-3, Q=4-7). Interval = {MFMA for one quad || activation
// for the other} + ONE barrier. P: MFMA@even/act@odd intervals; Q shifted by
// one. MFMA and VALU/trans are separate pipes (m114) and the two streams are
// independent -> overlap fills r11's alternating-pipe idle (r11: 467 VALU +
// 380 MFMA busy of 1460 cyc/step). All tile math / swizzles / L1 skew
// byte-identical to r11 (proven absmax 4.88e-4). r13 lesson: no giant pinned
// sets — live regs ~110 < 128 cap.
// MFMA job split (8 waves x 12): wave wv owns (g,j) pairs q0=2wv, q1=2wv+1
// (g=q>>2, j=q&3), each pair = L0 tile (2 MFMAs) + L1 tile (4 MFMAs).
// Act: lane owns one (L,unit,elem-in-quad) for BOTH quads (c0q/c1q scalars).
__global__ __launch_bounds__(NTHR, 2) __attribute__((amdgpu_waves_per_eu(2, 2)))
void lstm_anti_kernel(const float* __restrict__ x,      // [B,T]
                      const float* __restrict__ w_ih0,  // [256,1]
                      const float* __restrict__ w_hh0,  // [256,64]
                      const float* __restrict__ b_ih0,  // [256]
                      const float* __restrict__ b_hh0,  // [256]
                      const float* __restrict__ w_ih1,  // [256,64]
                      const float* __restrict__ w_hh1,  // [256,64]
                      const float* __restrict__ b_ih1,  // [256]
                      const float* __restrict__ b_hh1,  // [256]
                      const float* __restrict__ w1, const float* __restrict__ b1,
                      const float* __restrict__ w2, const float* __restrict__ b2,
                      const float* __restrict__ w3, const float* __restrict__ b3,
                      float* __restrict__ out)          // [B,10]
{
    const int tid = threadIdx.x;
    const int wv  = tid >> 6;        // wave 0..7
    const int l   = tid & 63;
    const int e16 = l & 15;          // MFMA col (elem-in-quad; valid < 4)
    const int kg  = l >> 4;          // k-group / C row-quad
    const int bA  = blockIdx.x * 8;
    const int g0  = (2 * wv) >> 2, j0 = (2 * wv) & 3;
    const int g1  = (2 * wv + 1) >> 2, j1 = (2 * wv + 1) & 3;

    __shared__ __align__(16) float xs[8 * (TT + 1)];            // [e][2049]
    __shared__ __align__(16) float glds[2][2][4][4][72];        // [q][L][g][e][u pad]
    __shared__ __align__(16) _Float16 hsw[2][2][16 * 64];       // [L][q], swizzled
    __shared__ float cls1[8][HH];
    __shared__ float cls2[8][32];

    // zero h buffers (rows 4..15 stay zero -> benign B cols)
    for (int i = tid; i < 2 * 2 * 16 * 64; i += NTHR)
        ((_Float16*)hsw)[i] = (_Float16)0.0f;
    // stage x: [e][t] stride 2049, coalesced reads; pad t=TT with 0
    for (int i = tid; i < 8 * TT; i += NTHR) {
        const int e = i >> 11, t = i & (TT - 1);
        xs[e * (TT + 1) + t] = x[(size_t)(bA + e) * TT + t];
    }
    if (tid < 8) xs[tid * (TT + 1) + TT] = 0.0f;

    // ---- MFMA weight frags: 12 half8 (r11-proven layout) ----
    // wf[m*6+{0,1}]=Whh0, {2,3}=Wih1, {4,5}=Whh1 for pair m's (g,j)
    half8 wf[12];
    {
        auto frag = [&](const float* M, int g, int j, int kc) {
            const int row = g * 64 + 16 * j + e16;   // A-frag row = l&15
            half8 v;
            #pragma unroll
            for (int i = 0; i < 8; ++i) v[i] = (_Float16)M[row * HH + kc * 32 + kg * 8 + i];
            return v;
        };
        wf[0]  = frag(w_hh0, g0, j0, 0); wf[1]  = frag(w_hh0, g0, j0, 1);
        wf[2]  = frag(w_ih1, g0, j0, 0); wf[3]  = frag(w_ih1, g0, j0, 1);
        wf[4]  = frag(w_hh1, g0, j0, 0); wf[5]  = frag(w_hh1, g0, j0, 1);
        wf[6]  = frag(w_hh0, g1, j1, 0); wf[7]  = frag(w_hh0, g1, j1, 1);
        wf[8]  = frag(w_ih1, g1, j1, 0); wf[9]  = frag(w_ih1, g1, j1, 1);
        wf[10] = frag(w_hh1, g1, j1, 0); wf[11] = frag(w_hh1, g1, j1, 1);
    }

    // ---- act identity: lane owns (L, unit au, elem ae) in each quad ----
    const int L  = tid >> 8;                  // wave-uniform: waves 0-3 L0, 4-7 L1
    const int au = 16 * (wv & 3) + (l >> 2);  // unit 0..63
    const int ae = l & 3;                     // elem-in-quad 0..3
    float bi[4], wxr[4];
    {
        const float* bihp = L ? b_ih1 : b_ih0;
        const float* bhhp = L ? b_hh1 : b_hh0;
        #pragma unroll
        for (int g = 0; g < 4; ++g) {
            bi[g]  = bihp[g * 64 + au] + bhhp[g * 64 + au];
            wxr[g] = L ? 0.0f : w_ih0[g * 64 + au];
        }
    }
    // pin (rounds 1-4 lesson); total pinned = 48+8 regs, safe under cap
    #pragma unroll
    for (int i = 0; i < 12; ++i) asm volatile("" : "+v"(wf[i]));
    #pragma unroll
    for (int g = 0; g < 4; ++g) {
        asm volatile("" : "+v"(bi[g]));
        asm volatile("" : "+v"(wxr[g]));
    }

    float cP = 0.0f, cQ = 0.0f;      // lane's cell state per quad

    const int swz16 = (e16 & 7) << 4;
    const int hro0 = e16 * 128 + ((16 * kg) ^ swz16);
    const int hro1 = e16 * 128 + ((64 + 16 * kg) ^ swz16);
    const int hwb  = ae * 128 + ((2 * au) ^ (ae << 4));   // act h write byte
    const int u0a = 16 * j0 + 4 * kg, u0b = 16 * j1 + 4 * kg;
    const f32x4 z4 = {0.0f, 0.0f, 0.0f, 0.0f};

    // MFMA phase for quad q (gates0(s)=Whh0.h0(s-1); gates1(s-1)=Wih1.h0(s-1)+Whh1.h1(s-2))
    auto MFMA_PHASE = [&](int q) {
        const char* h0r = (const char*)&hsw[0][q][0];
        const char* h1r = (const char*)&hsw[1][q][0];
        half8 f0 = *(const half8*)(h0r + hro0);
        half8 f1 = *(const half8*)(h0r + hro1);
        half8 f2 = *(const half8*)(h1r + hro0);
        half8 f3 = *(const half8*)(h1r + hro1);
        f32x4 a0, a1, b0, b1v;
        a0 = __builtin_amdgcn_mfma_f32_16x16x32_f16(wf[0], f0, z4, 0, 0, 0);
        a0 = __builtin_amdgcn_mfma_f32_16x16x32_f16(wf[1], f1, a0, 0, 0, 0);
        a1 = __builtin_amdgcn_mfma_f32_16x16x32_f16(wf[2], f0, z4, 0, 0, 0);
        a1 = __builtin_amdgcn_mfma_f32_16x16x32_f16(wf[3], f1, a1, 0, 0, 0);
        a1 = __builtin_amdgcn_mfma_f32_16x16x32_f16(wf[4], f2, a1, 0, 0, 0);
        a1 = __builtin_amdgcn_mfma_f32_16x16x32_f16(wf[5], f3, a1, 0, 0, 0);
        b0 = __builtin_amdgcn_mfma_f32_16x16x32_f16(wf[6], f0, z4, 0, 0, 0);
        b0 = __builtin_amdgcn_mfma_f32_16x16x32_f16(wf[7], f1, b0, 0, 0, 0);
        b1v = __builtin_amdgcn_mfma_f32_16x16x32_f16(wf[8],  f0, z4, 0, 0, 0);
        b1v = __builtin_amdgcn_mfma_f32_16x16x32_f16(wf[9],  f1, b1v, 0, 0, 0);
        b1v = __builtin_amdgcn_mfma_f32_16x16x32_f16(wf[10], f2, b1v, 0, 0, 0);
        b1v = __builtin_amdgcn_mfma_f32_16x16x32_f16(wf[11], f3, b1v, 0, 0, 0);
        if (e16 < 4) {
            *(f32x4*)&glds[q][0][g0][e16][u0a] = a0;
            *(f32x4*)&glds[q][1][g0][e16][u0a] = a1;
            *(f32x4*)&glds[q][0][g1][e16][u0b] = b0;
            *(f32x4*)&glds[q][1][g1][e16][u0b] = b1v;
        }
    };

    // act phase for quad q at step s (updates cell c by reference)
    auto ACT_PHASE = [&](int q, int s, float& c) {
        float z0 = glds[q][L][0][ae][au];
        float z1 = glds[q][L][1][ae][au];
        float z2 = glds[q][L][2][ae][au];
        float z3 = glds[q][L][3][ae][au];
        const float xt = xs[(q * 4 + ae) * (TT + 1) + s];
        z0 += fmaf(wxr[0], xt, bi[0]);
        z1 += fmaf(wxr[1], xt, bi[1]);
        z2 += fmaf(wxr[2], xt, bi[2]);
        z3 += fmaf(wxr[3], xt, bi[3]);
        float gi = sigmoid_fast(z0);
        float gf = sigmoid_fast(z1);
        float gg = tanh_fast(z2);
        float go = sigmoid_fast(z3);
        c = fmaf(gf, c, gi * gg);
        float h = go * tanh_fast(c);
        if (L && s == 0) { c = 0.0f; h = 0.0f; }   // enforce h1(-1)=0
        *(_Float16*)((char*)&hsw[L][q][0] + hwb) = (_Float16)h;
    };

    __syncthreads();

    for (int kk = 0; kk < TT + 2; ++kk) {
        // even interval: MFMA(P=quad0, s=kk)  ||  act(Q=quad1, s=kk-1)
        if (kk <= TT) MFMA_PHASE(0);
        if (kk >= 1)  ACT_PHASE(1, kk - 1, cQ);
        __syncthreads();
        // odd interval: MFMA(Q=quad1, s=kk)  ||  act(P=quad0, s=kk)
        if (kk <= TT) {
            MFMA_PHASE(1);
            ACT_PHASE(0, kk, cP);
        }
        __syncthreads();
    }
    // hsw[1][q] holds h1(TT-1) = h_last for each quad

    // ---- classifier head: wave wv handles elem wv (q=wv>>2, col=wv&3) ----
    {
        const int q = wv >> 2, col = wv & 3;
        const char* h1f = (const char*)&hsw[1][q][0];
        float a = b1[l];
        #pragma unroll 8
        for (int k = 0; k < HH; ++k) {
            const float hk = (float)*(const _Float16*)(h1f + col * 128 + ((2 * k) ^ (col << 4)));
            a = fmaf(w1[l * HH + k], hk, a);
        }
        cls1[wv][l] = fmaxf(a, 0.0f);
    }
    __syncthreads();
    if (l < 32) {
        float a = b2[l];
        #pragma unroll 8
        for (int k = 0; k < HH; ++k) a = fmaf(w2[l * HH + k], cls1[wv][k], a);
        cls2[wv][l] = fmaxf(a, 0.0f);
    }
    __syncthreads();
    if (l < 10) {
        float a = b3[l];
        #pragma unroll
        for (int k = 0; k < 32; ++k) a = fmaf(w3[l * 32 + k], cls2[wv][k], a);
        out[(size_t)(bA + wv) * 10 + l] = a;
    }
}

extern "C" void kernel_launch(void* const* d_in, const int* in_sizes, int n_in,
                              void* d_out, int out_size, void* d_ws, size_t ws_size,
                              hipStream_t stream) {
    const float* x     = (const float*)d_in[0];
    const float* w_ih0 = (const float*)d_in[1];
    const float* w_hh0 = (const float*)d_in[2];
    const float* b_ih0 = (const float*)d_in[3];
    const float* b_hh0 = (const float*)d_in[4];
    const float* w_ih1 = (const float*)d_in[5];
    const float* w_hh1 = (const float*)d_in[6];
    const float* b_ih1 = (const float*)d_in[7];
    const float* b_hh1 = (const float*)d_in[8];
    const float* w1    = (const float*)d_in[9];
    const float* b1    = (const float*)d_in[10];
    const float* w2    = (const float*)d_in[11];
    const float* b2    = (const float*)d_in[12];
    const float* w3    = (const float*)d_in[13];
    const float* b3    = (const float*)d_in[14];
    float* out = (float*)d_out;

    lstm_anti_kernel<<<NBLK, NTHR, 0, stream>>>(x, w_ih0, w_hh0, b_ih0, b_hh0,
                                                w_ih1, w_hh1, b_ih1, b_hh1,
                                                w1, b1, w2, b2, w3, b3, out);
}

// Round 15
// 1159.137 us; speedup vs baseline: 5.6733x; 1.9234x over previous
//
#include <hip/hip_runtime.h>
#include <math.h>

#define TT 2048
#define HH 64
#define NE 4       // batch elems per block
#define NBLK 128   // 512 / NE
#define NTHR 512   // 8 waves: (L = wv>>2, j = wv&3)

typedef _Float16 half8 __attribute__((ext_vector_type(8)));
typedef float f32x4 __attribute__((ext_vector_type(4)));

__device__ __forceinline__ float sigmoid_fast(float x) {
    float e = __expf(-x);
    return __builtin_amdgcn_rcpf(1.0f + e);
}
__device__ __forceinline__ float tanh_fast(float x) {
    float e = __expf(-2.0f * x);
    return fmaf(2.0f, __builtin_amdgcn_rcpf(1.0f + e), -1.0f);
}

// Round 15: single-phase merged step — ONE barrier per timestep.
// r11 proved the layout (1248us, 2 barriers/step, chain 1460cy); r14 proved
// wall time = per-block chain (grid shape irrelevant <=256 blocks) and that
// intra-wave "overlap" of two dependent phases is serial. So: cut the chain.
// Wave (L=wv>>2, j=wv&3) computes ALL 4 gate tiles of layer L for units
// [16j,16j+16) — uniform 16-MFMA code for both roles (L0's h1-slot weight
// frags are ZERO: mfma(0,.,acc)==acc exactly; balances both wave types,
// no divergent reg pressure). C-frags -> glds (wave-own range) -> SAME-WAVE
// readback (DS ops in a wave are in-order; no barrier) -> act 1 unit-elem
// per lane (10 trans) -> ping-pong swizzled h write -> one __syncthreads.
// Ping-pong: read parity t&1, write (t&1)^1 (WAR across waves). Arithmetic
// per gate identical to r11 -> absmax must stay 4.882812e-4.
__global__ __launch_bounds__(NTHR) __attribute__((amdgpu_waves_per_eu(4, 4)))
void lstm_merged_kernel(const float* __restrict__ x,      // [B,T]
                        const float* __restrict__ w_ih0,  // [256,1]
                        const float* __restrict__ w_hh0,  // [256,64]
                        const float* __restrict__ b_ih0,  // [256]
                        const float* __restrict__ b_hh0,  // [256]
                        const float* __restrict__ w_ih1,  // [256,64]
                        const float* __restrict__ w_hh1,  // [256,64]
                        const float* __restrict__ b_ih1,  // [256]
                        const float* __restrict__ b_hh1,  // [256]
                        const float* __restrict__ w1, const float* __restrict__ b1,
                        const float* __restrict__ w2, const float* __restrict__ b2,
                        const float* __restrict__ w3, const float* __restrict__ b3,
                        float* __restrict__ out)          // [B,10]
{
    const int tid = threadIdx.x;
    const int wv  = tid >> 6;        // wave 0..7
    const int l   = tid & 63;
    const int L   = wv >> 2;         // layer this wave owns
    const int j   = wv & 3;          // unit group [16j, 16j+16)
    const int e16 = l & 15;          // MFMA col (elem; valid < NE)
    const int kg  = l >> 4;          // k-group / C row-quad
    const int bA  = blockIdx.x * NE;

    __shared__ __align__(16) float xs[(TT + 1) * (NE + 1)];    // [t][5] pad
    __shared__ __align__(16) float glds[2][4][NE][72];         // [L][g][e][u pad]
    __shared__ __align__(16) _Float16 hsw[2][2][16 * 64];      // [L][parity] swizzled
    __shared__ float cls1[NE][HH];
    __shared__ float cls2[NE][32];

    // zero h buffers (rows 4..15 stay zero -> benign B cols)
    for (int i = tid; i < 2 * 2 * 16 * 64; i += NTHR)
        ((_Float16*)hsw)[i] = (_Float16)0.0f;
    // stage x: xs[t*5+e] (stride-5 conflict-free), coalesced reads; pad t=TT
    for (int i = tid; i < NE * TT; i += NTHR) {
        const int e = i >> 11, t = i & (TT - 1);
        xs[t * (NE + 1) + e] = x[(size_t)(bA + e) * TT + t];
    }
    if (tid < NE + 1) xs[TT * (NE + 1) + tid] = 0.0f;

    // ---- weight A-frags (fp16), uniform 16-slot layout ----
    // wf[4g+0,1] = (L ? Wih1 : Whh0)(g,j) kc=0,1
    // wf[4g+2,3] = L ? Whh1(g,j) kc=0,1 : ZERO (mfma no-op keeps L0 exact)
    half8 wf[16];
    {
        auto frag = [&](const float* M, int g, int kc) {
            const int row = g * 64 + 16 * j + e16;   // A-frag row = l&15
            half8 v;
            #pragma unroll
            for (int i = 0; i < 8; ++i) v[i] = (_Float16)M[row * HH + kc * 32 + kg * 8 + i];
            return v;
        };
        const float* M01 = L ? w_ih1 : w_hh0;
        #pragma unroll
        for (int g = 0; g < 4; ++g) {
            wf[4 * g + 0] = frag(M01, g, 0);
            wf[4 * g + 1] = frag(M01, g, 1);
            if (L) {
                wf[4 * g + 2] = frag(w_hh1, g, 0);
                wf[4 * g + 3] = frag(w_hh1, g, 1);
            } else {
                half8 zz;
                #pragma unroll
                for (int i = 0; i < 8; ++i) zz[i] = (_Float16)0.0f;
                wf[4 * g + 2] = zz;
                wf[4 * g + 3] = zz;
            }
        }
    }

    // ---- act identity: lane owns (L, unit au, elem ae) ----
    const int au = 16 * j + (l >> 2);    // unit, within wave's own group
    const int ae = l & 3;                // elem
    float bi[4], wxr[4];
    {
        const float* bihp = L ? b_ih1 : b_ih0;
        const float* bhhp = L ? b_hh1 : b_hh0;
        #pragma unroll
        for (int g = 0; g < 4; ++g) {
            bi[g]  = bihp[g * 64 + au] + bhhp[g * 64 + au];
            wxr[g] = L ? 0.0f : w_ih0[g * 64 + au];
        }
    }
    // pin (rounds 1-4 lesson: allocator rematerializes weight loads otherwise)
    #pragma unroll
    for (int i = 0; i < 16; ++i) asm volatile("" : "+v"(wf[i]));
    #pragma unroll
    for (int g = 0; g < 4; ++g) {
        asm volatile("" : "+v"(bi[g]));
        asm volatile("" : "+v"(wxr[g]));
    }

    float c = 0.0f;                      // lane's cell state (unit au, elem ae)

    const int swz16 = (e16 & 7) << 4;
    const int hro0 = e16 * 128 + ((16 * kg) ^ swz16);        // k-chunk 0
    const int hro1 = e16 * 128 + ((64 + 16 * kg) ^ swz16);   // k-chunk 1
    const int hwb  = ae * 128 + ((2 * au) ^ (ae << 4));      // act h write byte
    const int u0   = 16 * j + 4 * kg;
    const f32x4 z4 = {0.0f, 0.0f, 0.0f, 0.0f};

    __syncthreads();

    for (int t = 0; t <= TT; ++t) {
        const int rp = t & 1;            // read parity
        // ---- MFMA: gates(L==0: gates0(t); L==1: gates1(t-1)), raw, no bias ----
        {
            const char* h0r = (const char*)&hsw[0][rp][0];
            const char* h1r = (const char*)&hsw[1][rp][0];
            half8 f0 = *(const half8*)(h0r + hro0);
            half8 f1 = *(const half8*)(h0r + hro1);
            half8 f2 = *(const half8*)(h1r + hro0);
            half8 f3 = *(const half8*)(h1r + hro1);
            f32x4 acc[4];
            #pragma unroll
            for (int g = 0; g < 4; ++g) {
                acc[g] = __builtin_amdgcn_mfma_f32_16x16x32_f16(wf[4 * g + 0], f0, z4, 0, 0, 0);
                acc[g] = __builtin_amdgcn_mfma_f32_16x16x32_f16(wf[4 * g + 1], f1, acc[g], 0, 0, 0);
                acc[g] = __builtin_amdgcn_mfma_f32_16x16x32_f16(wf[4 * g + 2], f2, acc[g], 0, 0, 0);
                acc[g] = __builtin_amdgcn_mfma_f32_16x16x32_f16(wf[4 * g + 3], f3, acc[g], 0, 0, 0);
            }
            if (e16 < NE) {
                #pragma unroll
                for (int g = 0; g < 4; ++g)
                    *(f32x4*)&glds[L][g][e16][u0] = acc[g];
            }
        }
        // ---- same-wave readback + act (1 unit-elem/lane, 10 trans) ----
        {
            float z0 = glds[L][0][ae][au];
            float z1 = glds[L][1][ae][au];
            float z2 = glds[L][2][ae][au];
            float z3 = glds[L][3][ae][au];
            const float xt = xs[t * (NE + 1) + ae];
            z0 += fmaf(wxr[0], xt, bi[0]);
            z1 += fmaf(wxr[1], xt, bi[1]);
            z2 += fmaf(wxr[2], xt, bi[2]);
            z3 += fmaf(wxr[3], xt, bi[3]);
            float gi = sigmoid_fast(z0);
            float gf = sigmoid_fast(z1);
            float gg = tanh_fast(z2);
            float go = sigmoid_fast(z3);
            c = fmaf(gf, c, gi * gg);
            float h = go * tanh_fast(c);
            if (L && t == 0) { c = 0.0f; h = 0.0f; }   // enforce h1(-1)=0
            *(_Float16*)((char*)&hsw[L][rp ^ 1][0] + hwb) = (_Float16)h;
        }
        __syncthreads();
    }
    // h_last = h1(TT-1), written at t=TT into parity (TT&1)^1 = 1

    // ---- classifier head: wave wv<4 handles elem wv ----
    if (wv < 4) {
        const char* h1f = (const char*)&hsw[1][1][0];
        float a = b1[l];
        #pragma unroll 8
        for (int k = 0; k < HH; ++k) {
            const float hk = (float)*(const _Float16*)(h1f + wv * 128 + ((2 * k) ^ (wv << 4)));
            a = fmaf(w1[l * HH + k], hk, a);
        }
        cls1[wv][l] = fmaxf(a, 0.0f);
    }
    __syncthreads();
    if (wv < 4 && l < 32) {
        float a = b2[l];
        #pragma unroll 8
        for (int k = 0; k < HH; ++k) a = fmaf(w2[l * HH + k], cls1[wv][k], a);
        cls2[wv][l] = fmaxf(a, 0.0f);
    }
    __syncthreads();
    if (wv < 4 && l < 10) {
        float a = b3[l];
        #pragma unroll
        for (int k = 0; k < 32; ++k) a = fmaf(w3[l * 32 + k], cls2[wv][k], a);
        out[(size_t)(bA + wv) * 10 + l] = a;
    }
}

extern "C" void kernel_launch(void* const* d_in, const int* in_sizes, int n_in,
                              void* d_out, int out_size, void* d_ws, size_t ws_size,
                              hipStream_t stream) {
    const float* x     = (const float*)d_in[0];
    const float* w_ih0 = (const float*)d_in[1];
    const float* w_hh0 = (const float*)d_in[2];
    const float* b_ih0 = (const float*)d_in[3];
    const float* b_hh0 = (const float*)d_in[4];
    const float* w_ih1 = (const float*)d_in[5];
    const float* w_hh1 = (const float*)d_in[6];
    const float* b_ih1 = (const float*)d_in[7];
    const float* b_hh1 = (const float*)d_in[8];
    const float* w1    = (const float*)d_in[9];
    const float* b1    = (const float*)d_in[10];
    const float* w2    = (const float*)d_in[11];
    const float* b2    = (const float*)d_in[12];
    const float* w3    = (const float*)d_in[13];
    const float* b3    = (const float*)d_in[14];
    float* out = (float*)d_out;

    lstm_merged_kernel<<<NBLK, NTHR, 0, stream>>>(x, w_ih0, w_hh0, b_ih0, b_hh0,
                                                  w_ih1, w_hh1, b_ih1, b_hh1,
                                                  w1, b1, w2, b2, w3, b3, out);
}